// Round 7
// baseline (638.138 us; speedup 1.0000x reference)
//
#include <hip/hip_runtime.h>
#include <stdint.h>

#define N_NODES 50000
#define N_EDGES 800000
#define F0 512
#define F1 256
#define F2 128
#define CAP 64   // Poisson(16) in-degree: P(deg>64) ~ 2e-18/node

// ==== JAX threefry2x32, key=(0,42), partitionable, 32-bit draw = x0 ^ x1 ====
// jax_threefry_partitionable=True (default, x64 off): element i -> counter
// (c0,c1) = (0, i); threefry outputs (bits1, bits2); 32-bit draw combines BOTH
// words: bits = bits1 ^ bits2 (jax/_src/prng.py partitionable path).
// uniform f32: u = bitcast((bits>>9)|0x3f800000)-1; keep <=> u < 0.8f
// <=> (bits>>9) < 0x666667.
__device__ __forceinline__ uint32_t r7_rotl(uint32_t x, int r) {
    return (x << r) | (x >> (32 - r));
}

__device__ __forceinline__ uint32_t r7_bits32(uint32_t idx) {
    const uint32_t ks0 = 0u;
    const uint32_t ks1 = 42u;
    const uint32_t ks2 = 0x1BD11BDAu ^ ks0 ^ ks1;  // 0x1BD11BF0
    uint32_t x0 = ks0;        // c0 = 0
    uint32_t x1 = idx + ks1;  // c1 = idx
#define R7R(r) { x0 += x1; x1 = r7_rotl(x1, (r)); x1 ^= x0; }
    R7R(13) R7R(15) R7R(26) R7R(6)
    x0 += ks1; x1 += ks2 + 1u;
    R7R(17) R7R(29) R7R(16) R7R(24)
    x0 += ks2; x1 += ks0 + 2u;
    R7R(13) R7R(15) R7R(26) R7R(6)
    x0 += ks0; x1 += ks1 + 3u;
    R7R(17) R7R(29) R7R(16) R7R(24)
    x0 += ks1; x1 += ks2 + 4u;
    R7R(13) R7R(15) R7R(26) R7R(6)
    x0 += ks2; x1 += ks0 + 5u;
#undef R7R
    return x0 ^ x1;  // partitionable 32-bit combine: XOR of both output words
}

__device__ __forceinline__ int r7_keep(uint32_t idx) {
    uint32_t bits = r7_bits32(idx);
    return (bits >> 9) < 0x666667u;  // u < 0.8f, exact integer form
}

// ======= graph prep =======
__global__ void r7_zero(int* __restrict__ p, int n) {
    int i = blockIdx.x * 256 + threadIdx.x;
    if (i < n) p[i] = 0;
}

// Detect int64 edge layout: values < 50000, so if int64, all odd 32-bit words == 0.
__global__ void r7_detect(const uint32_t* __restrict__ ei, int* __restrict__ flag) {
    int t = threadIdx.x;  // 0..63
    uint32_t v = ei[2 * t + 1] | ei[128 + 2 * t + 1];
    unsigned long long any_nonzero = __ballot(v != 0u);
    if (t == 0) flag[0] = (any_nonzero == 0ull) ? 1 : 0;
}

__global__ void r7_fill(const int* __restrict__ ei, const int* __restrict__ flag,
                        int* __restrict__ cursor, int* __restrict__ bucket) {
    int e = blockIdx.x * 256 + threadIdx.x;
    if (e < N_EDGES) {
        int f = flag[0];  // 0: int32, 1: int64 (read low words)
        int s = ei[(size_t)e << f];
        int d = ei[(size_t)(N_EDGES + e) << f];
        int pos = atomicAdd(&cursor[d], 1);
        if (pos < CAP) bucket[(size_t)d * CAP + pos] = s;
    }
}

__global__ void r7_dinv(const int* __restrict__ cursor, float* __restrict__ dinv) {
    int v = blockIdx.x * 256 + threadIdx.x;
    if (v < N_NODES) dinv[v] = 1.0f / sqrtf((float)(cursor[v] + 1));  // +1 self loop
}

// ======= f32 tiled GEMM: C[M,N] = A[M,K] @ B[K,N] =======
// 64x64 tile, BK=16, 256 threads, 4x4 microtile. K%16==0, N%64==0.
__global__ __launch_bounds__(256)
void r7_sgemm(const float* __restrict__ A, const float* __restrict__ B,
              float* __restrict__ C, int M, int N, int K) {
    __shared__ float As[16][64];
    __shared__ float Bs[16][64];
    const int bm = blockIdx.x * 64;
    const int bn = blockIdx.y * 64;
    const int tid = threadIdx.x;
    const int tr = (tid >> 4) << 2;
    const int tc = (tid & 15) << 2;
    const int arow = tid >> 2;
    const int acol = (tid & 3) << 2;
    const int brow = tid >> 4;
    const int bcol = (tid & 15) << 2;

    float acc[4][4] = {{0.f}};
    for (int k0 = 0; k0 < K; k0 += 16) {
        float4 av = make_float4(0.f, 0.f, 0.f, 0.f);
        if (bm + arow < M)
            av = *(const float4*)(A + (size_t)(bm + arow) * K + (k0 + acol));
        As[acol + 0][arow] = av.x;
        As[acol + 1][arow] = av.y;
        As[acol + 2][arow] = av.z;
        As[acol + 3][arow] = av.w;
        *(float4*)&Bs[brow][bcol] =
            *(const float4*)(B + (size_t)(k0 + brow) * N + (bn + bcol));
        __syncthreads();
#pragma unroll
        for (int kk = 0; kk < 16; ++kk) {
            float4 a = *(const float4*)&As[kk][tr];
            float4 b = *(const float4*)&Bs[kk][tc];
            acc[0][0] += a.x * b.x; acc[0][1] += a.x * b.y; acc[0][2] += a.x * b.z; acc[0][3] += a.x * b.w;
            acc[1][0] += a.y * b.x; acc[1][1] += a.y * b.y; acc[1][2] += a.y * b.z; acc[1][3] += a.y * b.w;
            acc[2][0] += a.z * b.x; acc[2][1] += a.z * b.y; acc[2][2] += a.z * b.z; acc[2][3] += a.z * b.w;
            acc[3][0] += a.w * b.x; acc[3][1] += a.w * b.y; acc[3][2] += a.w * b.z; acc[3][3] += a.w * b.w;
        }
        __syncthreads();
    }
#pragma unroll
    for (int i = 0; i < 4; ++i) {
        int row = bm + tr + i;
        if (row < M)
            *(float4*)(C + (size_t)row * N + bn + tc) =
                make_float4(acc[i][0], acc[i][1], acc[i][2], acc[i][3]);
    }
}

// ======= propagation 1 + bias + ReLU + dropout (f64 accumulate) =======
// one wave per node; 4 features per lane (256 total)
__global__ __launch_bounds__(64)
void r7_prop1(const float* __restrict__ h1, const int* __restrict__ bucket,
              const int* __restrict__ deg, const float* __restrict__ dinv,
              const float* __restrict__ b1, float* __restrict__ a1) {
    const int v = blockIdx.x;
    const int t = threadIdx.x;
    const float dv = dinv[v];
    const size_t off = (size_t)v * F1 + t * 4;
    float4 h = *(const float4*)(h1 + off);
    const double w0 = (double)dv * (double)dv;
    double ax = h.x * w0, ay = h.y * w0, az = h.z * w0, aw = h.w * w0;
    int cnt = deg[v]; if (cnt > CAP) cnt = CAP;
    const int* bk = bucket + (size_t)v * CAP;
    for (int j = 0; j < cnt; ++j) {
        int s = bk[j];
        double w = (double)dinv[s] * (double)dv;
        float4 hs = *(const float4*)(h1 + (size_t)s * F1 + t * 4);
        ax += hs.x * w; ay += hs.y * w; az += hs.z * w; aw += hs.w * w;
    }
    float4 bb = *(const float4*)(b1 + t * 4);
    ax += bb.x; ay += bb.y; az += bb.z; aw += bb.w;
    ax = ax > 0.0 ? ax : 0.0;
    ay = ay > 0.0 ? ay : 0.0;
    az = az > 0.0 ? az : 0.0;
    aw = aw > 0.0 ? aw : 0.0;
    uint32_t idx = (uint32_t)v * F1 + (uint32_t)t * 4;
    float4 r;
    r.x = r7_keep(idx + 0) ? (float)(ax / 0.8) : 0.0f;
    r.y = r7_keep(idx + 1) ? (float)(ay / 0.8) : 0.0f;
    r.z = r7_keep(idx + 2) ? (float)(az / 0.8) : 0.0f;
    r.w = r7_keep(idx + 3) ? (float)(aw / 0.8) : 0.0f;
    *(float4*)(a1 + off) = r;
}

// ======= propagation 2 + bias + softmax (f64 accumulate) =======
// one wave per node; 2 features per lane (128 total)
__global__ __launch_bounds__(64)
void r7_prop2(const float* __restrict__ h2, const int* __restrict__ bucket,
              const int* __restrict__ deg, const float* __restrict__ dinv,
              const float* __restrict__ b2, float* __restrict__ out) {
    const int v = blockIdx.x;
    const int t = threadIdx.x;
    const float dv = dinv[v];
    const size_t off = (size_t)v * F2 + t * 2;
    float2 h = *(const float2*)(h2 + off);
    const double w0 = (double)dv * (double)dv;
    double ax = h.x * w0, ay = h.y * w0;
    int cnt = deg[v]; if (cnt > CAP) cnt = CAP;
    const int* bk = bucket + (size_t)v * CAP;
    for (int j = 0; j < cnt; ++j) {
        int s = bk[j];
        double w = (double)dinv[s] * (double)dv;
        float2 hs = *(const float2*)(h2 + (size_t)s * F2 + t * 2);
        ax += hs.x * w; ay += hs.y * w;
    }
    float2 bb = *(const float2*)(b2 + t * 2);
    float lx = (float)(ax + bb.x);
    float ly = (float)(ay + bb.y);
    float m = fmaxf(lx, ly);
#pragma unroll
    for (int o = 32; o >= 1; o >>= 1) m = fmaxf(m, __shfl_xor(m, o, 64));
    float ex = expf(lx - m), ey = expf(ly - m);
    float s = ex + ey;
#pragma unroll
    for (int o = 32; o >= 1; o >>= 1) s += __shfl_xor(s, o, 64);
    float inv = 1.0f / s;
    *(float2*)(out + off) = make_float2(ex * inv, ey * inv);
}

// ======= launch =======
extern "C" void kernel_launch(void* const* d_in, const int* in_sizes, int n_in,
                              void* d_out, int out_size, void* d_ws, size_t ws_size,
                              hipStream_t stream) {
    const float* x  = (const float*)d_in[0];
    const int*   ei = (const int*)d_in[1];
    const float* W1 = (const float*)d_in[2];
    const float* b1 = (const float*)d_in[3];
    const float* W2 = (const float*)d_in[4];
    const float* b2 = (const float*)d_in[5];
    float* out = (float*)d_out;

    char* ws = (char*)d_ws;
    size_t o = 0;
    auto alloc = [&](size_t bytes) -> char* {
        char* p = ws + o;
        o += (bytes + 511) & ~(size_t)511;
        return p;
    };
    int*   flag   = (int*)  alloc(4);
    int*   cursor = (int*)  alloc((size_t)N_NODES * 4);
    float* dinv   = (float*)alloc((size_t)N_NODES * 4);
    int*   bucket = (int*)  alloc((size_t)N_NODES * CAP * 4);
    float* h1     = (float*)alloc((size_t)N_NODES * F1 * 4);
    float* a1     = (float*)alloc((size_t)N_NODES * F1 * 4);

    r7_zero<<<(N_NODES + 255) / 256, 256, 0, stream>>>(cursor, N_NODES);
    r7_detect<<<1, 64, 0, stream>>>((const uint32_t*)ei, flag);
    r7_fill<<<(N_EDGES + 255) / 256, 256, 0, stream>>>(ei, flag, cursor, bucket);
    r7_dinv<<<(N_NODES + 255) / 256, 256, 0, stream>>>(cursor, dinv);

    dim3 g1((N_NODES + 63) / 64, F1 / 64);
    r7_sgemm<<<g1, 256, 0, stream>>>(x, W1, h1, N_NODES, F1, F0);

    r7_prop1<<<N_NODES, 64, 0, stream>>>(h1, bucket, cursor, dinv, b1, a1);

    float* h2 = h1;  // h1 dead after prop1; reuse as layer-2 GEMM output
    dim3 g2((N_NODES + 63) / 64, F2 / 64);
    r7_sgemm<<<g2, 256, 0, stream>>>(a1, W2, h2, N_NODES, F2, F1);

    r7_prop2<<<N_NODES, 64, 0, stream>>>(h2, bucket, cursor, dinv, b2, out);
}

// Round 8
// 483.647 us; speedup vs baseline: 1.3194x; 1.3194x over previous
//
#include <hip/hip_runtime.h>
#include <stdint.h>

#define N_NODES 50000
#define N_EDGES 800000
#define F0 512
#define F1 256
#define F2 128
#define CAP 64   // Poisson(16) in-degree: P(deg>64) ~ 2e-18/node

typedef __attribute__((ext_vector_type(8))) short short8;
typedef __attribute__((ext_vector_type(4))) float float4v;

// ==== JAX threefry2x32, key=(0,42), partitionable, 32-bit draw = x0 ^ x1 ====
__device__ __forceinline__ uint32_t r8_rotl(uint32_t x, int r) {
    return (x << r) | (x >> (32 - r));
}

__device__ __forceinline__ uint32_t r8_bits32(uint32_t idx) {
    const uint32_t ks0 = 0u;
    const uint32_t ks1 = 42u;
    const uint32_t ks2 = 0x1BD11BDAu ^ ks0 ^ ks1;  // 0x1BD11BF0
    uint32_t x0 = ks0;        // c0 = 0
    uint32_t x1 = idx + ks1;  // c1 = idx
#define R8R(r) { x0 += x1; x1 = r8_rotl(x1, (r)); x1 ^= x0; }
    R8R(13) R8R(15) R8R(26) R8R(6)
    x0 += ks1; x1 += ks2 + 1u;
    R8R(17) R8R(29) R8R(16) R8R(24)
    x0 += ks2; x1 += ks0 + 2u;
    R8R(13) R8R(15) R8R(26) R8R(6)
    x0 += ks0; x1 += ks1 + 3u;
    R8R(17) R8R(29) R8R(16) R8R(24)
    x0 += ks1; x1 += ks2 + 4u;
    R8R(13) R8R(15) R8R(26) R8R(6)
    x0 += ks2; x1 += ks0 + 5u;
#undef R8R
    return x0 ^ x1;  // partitionable 32-bit combine
}

__device__ __forceinline__ int r8_keep(uint32_t idx) {
    return (r8_bits32(idx) >> 9) < 0x666667u;  // u < 0.8f, exact integer form
}

__device__ __forceinline__ unsigned short r8_f2bf(float f) {
    uint32_t u = __float_as_uint(f);
    uint32_t r = u + 0x7fffu + ((u >> 16) & 1u);  // RNE
    return (unsigned short)(r >> 16);
}

// ======= graph prep =======
__global__ void r8_zero(int* __restrict__ p, int n) {
    int i = blockIdx.x * 256 + threadIdx.x;
    if (i < n) p[i] = 0;
}

__global__ void r8_detect(const uint32_t* __restrict__ ei, int* __restrict__ flag) {
    int t = threadIdx.x;  // 0..63
    uint32_t v = ei[2 * t + 1] | ei[128 + 2 * t + 1];
    unsigned long long any_nonzero = __ballot(v != 0u);
    if (t == 0) flag[0] = (any_nonzero == 0ull) ? 1 : 0;
}

__global__ void r8_fill(const int* __restrict__ ei, const int* __restrict__ flag,
                        int* __restrict__ cursor, int* __restrict__ bucket) {
    int e = blockIdx.x * 256 + threadIdx.x;
    if (e < N_EDGES) {
        int f = flag[0];  // 0: int32, 1: int64 (read low words)
        int s = ei[(size_t)e << f];
        int d = ei[(size_t)(N_EDGES + e) << f];
        int pos = atomicAdd(&cursor[d], 1);
        if (pos < CAP) bucket[(size_t)d * CAP + pos] = s;
    }
}

__global__ void r8_dinv(const int* __restrict__ cursor, float* __restrict__ dinv) {
    int v = blockIdx.x * 256 + threadIdx.x;
    if (v < N_NODES) dinv[v] = 1.0f / sqrtf((float)(cursor[v] + 1));  // +1 self loop
}

// W1 f32 [512][256] -> W1^T bf16 [256][512]
__global__ void r8_w1t(const float* __restrict__ W1, unsigned short* __restrict__ Bt) {
    int k = blockIdx.x;       // 0..511
    int n = threadIdx.x;      // 0..255
    Bt[(size_t)n * F0 + k] = r8_f2bf(W1[(size_t)k * F1 + n]);
}

// ======= bf16 MFMA GEMM1: h1[M,256] = x[M,512] @ W1, A converted inline =======
// 128x128 block tile, BK=32, 256 threads = 4 waves (2x2), each wave 64x64 via
// 4x4 grid of 16x16x32 MFMAs. LDS row stride 40 bf16 (80 B) -> <=2-way bank alias.
#define G1_LDA 40
__global__ __launch_bounds__(256)
void r8_gemm1(const float* __restrict__ A, const unsigned short* __restrict__ Bt,
              float* __restrict__ C, int M) {
    __shared__ unsigned short As[128][G1_LDA];
    __shared__ unsigned short Bs[128][G1_LDA];
    const int bm = blockIdx.x * 128;
    const int bn = blockIdx.y * 128;
    const int tid = threadIdx.x;
    const int wave = tid >> 6;
    const int lane = tid & 63;
    const int wm = (wave & 1) * 64;
    const int wn = (wave >> 1) * 64;
    const int l15 = lane & 15;
    const int quad = lane >> 4;

    const int sr = tid >> 1;              // staging row 0..127
    const int sk = (tid & 1) * 16;        // staging k offset 0 / 16

    float4v acc[4][4];
#pragma unroll
    for (int i = 0; i < 4; ++i)
#pragma unroll
        for (int j = 0; j < 4; ++j) acc[i][j] = (float4v){0.f, 0.f, 0.f, 0.f};

    const int arow = bm + sr;
    const bool avalid = arow < M;
    const float* aptr = A + (size_t)(avalid ? arow : 0) * F0 + sk;
    const unsigned short* bptr = Bt + (size_t)(bn + sr) * F0 + sk;

    for (int k0 = 0; k0 < F0; k0 += 32) {
        // stage A: 16 f32 -> 16 bf16 per thread
        union { short8 v[2]; unsigned short u[16]; } at;
        if (avalid) {
            const float4* ap = (const float4*)(aptr + k0);
#pragma unroll
            for (int q = 0; q < 4; ++q) {
                float4 f = ap[q];
                at.u[q * 4 + 0] = r8_f2bf(f.x);
                at.u[q * 4 + 1] = r8_f2bf(f.y);
                at.u[q * 4 + 2] = r8_f2bf(f.z);
                at.u[q * 4 + 3] = r8_f2bf(f.w);
            }
        } else {
#pragma unroll
            for (int q = 0; q < 16; ++q) at.u[q] = 0;
        }
        *(short8*)&As[sr][sk] = at.v[0];
        *(short8*)&As[sr][sk + 8] = at.v[1];
        // stage B (already bf16)
        *(short8*)&Bs[sr][sk] = *(const short8*)(bptr + k0);
        *(short8*)&Bs[sr][sk + 8] = *(const short8*)(bptr + k0 + 8);
        __syncthreads();

        short8 afr[4], bfr[4];
#pragma unroll
        for (int mi = 0; mi < 4; ++mi)
            afr[mi] = *(const short8*)&As[wm + mi * 16 + l15][quad * 8];
#pragma unroll
        for (int ni = 0; ni < 4; ++ni)
            bfr[ni] = *(const short8*)&Bs[wn + ni * 16 + l15][quad * 8];
#pragma unroll
        for (int mi = 0; mi < 4; ++mi)
#pragma unroll
            for (int ni = 0; ni < 4; ++ni)
                acc[mi][ni] = __builtin_amdgcn_mfma_f32_16x16x32_bf16(
                    afr[mi], bfr[ni], acc[mi][ni], 0, 0, 0);
        __syncthreads();
    }

    // epilogue: C/D layout col=lane&15, row=quad*4+reg
#pragma unroll
    for (int mi = 0; mi < 4; ++mi) {
#pragma unroll
        for (int r = 0; r < 4; ++r) {
            int row = bm + wm + mi * 16 + quad * 4 + r;
            if (row < M) {
                float* cp = C + (size_t)row * F1 + bn + wn + l15;
#pragma unroll
                for (int ni = 0; ni < 4; ++ni) cp[ni * 16] = acc[mi][ni][r];
            }
        }
    }
}

// ======= f32 tiled GEMM (layer 2): C[M,N] = A[M,K] @ B[K,N] =======
__global__ __launch_bounds__(256)
void r8_sgemm(const float* __restrict__ A, const float* __restrict__ B,
              float* __restrict__ C, int M, int N, int K) {
    __shared__ float As[16][64];
    __shared__ float Bs[16][64];
    const int bm = blockIdx.x * 64;
    const int bn = blockIdx.y * 64;
    const int tid = threadIdx.x;
    const int tr = (tid >> 4) << 2;
    const int tc = (tid & 15) << 2;
    const int arow = tid >> 2;
    const int acol = (tid & 3) << 2;
    const int brow = tid >> 4;
    const int bcol = (tid & 15) << 2;

    float acc[4][4] = {{0.f}};
    for (int k0 = 0; k0 < K; k0 += 16) {
        float4 av = make_float4(0.f, 0.f, 0.f, 0.f);
        if (bm + arow < M)
            av = *(const float4*)(A + (size_t)(bm + arow) * K + (k0 + acol));
        As[acol + 0][arow] = av.x;
        As[acol + 1][arow] = av.y;
        As[acol + 2][arow] = av.z;
        As[acol + 3][arow] = av.w;
        *(float4*)&Bs[brow][bcol] =
            *(const float4*)(B + (size_t)(k0 + brow) * N + (bn + bcol));
        __syncthreads();
#pragma unroll
        for (int kk = 0; kk < 16; ++kk) {
            float4 a = *(const float4*)&As[kk][tr];
            float4 b = *(const float4*)&Bs[kk][tc];
            acc[0][0] += a.x * b.x; acc[0][1] += a.x * b.y; acc[0][2] += a.x * b.z; acc[0][3] += a.x * b.w;
            acc[1][0] += a.y * b.x; acc[1][1] += a.y * b.y; acc[1][2] += a.y * b.z; acc[1][3] += a.y * b.w;
            acc[2][0] += a.z * b.x; acc[2][1] += a.z * b.y; acc[2][2] += a.z * b.z; acc[2][3] += a.z * b.w;
            acc[3][0] += a.w * b.x; acc[3][1] += a.w * b.y; acc[3][2] += a.w * b.z; acc[3][3] += a.w * b.w;
        }
        __syncthreads();
    }
#pragma unroll
    for (int i = 0; i < 4; ++i) {
        int row = bm + tr + i;
        if (row < M)
            *(float4*)(C + (size_t)row * N + bn + tc) =
                make_float4(acc[i][0], acc[i][1], acc[i][2], acc[i][3]);
    }
}

// ======= propagation 1 + bias + ReLU + dropout (f32) =======
__global__ __launch_bounds__(64)
void r8_prop1(const float* __restrict__ h1, const int* __restrict__ bucket,
              const int* __restrict__ deg, const float* __restrict__ dinv,
              const float* __restrict__ b1, float* __restrict__ a1) {
    const int v = blockIdx.x;
    const int t = threadIdx.x;
    const float dv = dinv[v];
    const size_t off = (size_t)v * F1 + t * 4;
    float4 h = *(const float4*)(h1 + off);
    const float w0 = dv * dv;
    float ax = h.x * w0, ay = h.y * w0, az = h.z * w0, aw = h.w * w0;
    int cnt = deg[v]; if (cnt > CAP) cnt = CAP;
    const int* bk = bucket + (size_t)v * CAP;
    for (int j = 0; j < cnt; ++j) {
        int s = bk[j];
        float w = dinv[s] * dv;
        float4 hs = *(const float4*)(h1 + (size_t)s * F1 + t * 4);
        ax += hs.x * w; ay += hs.y * w; az += hs.z * w; aw += hs.w * w;
    }
    float4 bb = *(const float4*)(b1 + t * 4);
    ax = fmaxf(ax + bb.x, 0.f);
    ay = fmaxf(ay + bb.y, 0.f);
    az = fmaxf(az + bb.z, 0.f);
    aw = fmaxf(aw + bb.w, 0.f);
    uint32_t idx = (uint32_t)v * F1 + (uint32_t)t * 4;
    float4 r;
    r.x = r8_keep(idx + 0) ? ax * 1.25f : 0.0f;
    r.y = r8_keep(idx + 1) ? ay * 1.25f : 0.0f;
    r.z = r8_keep(idx + 2) ? az * 1.25f : 0.0f;
    r.w = r8_keep(idx + 3) ? aw * 1.25f : 0.0f;
    *(float4*)(a1 + off) = r;
}

// ======= propagation 2 + bias + softmax (f32) =======
__global__ __launch_bounds__(64)
void r8_prop2(const float* __restrict__ h2, const int* __restrict__ bucket,
              const int* __restrict__ deg, const float* __restrict__ dinv,
              const float* __restrict__ b2, float* __restrict__ out) {
    const int v = blockIdx.x;
    const int t = threadIdx.x;
    const float dv = dinv[v];
    const size_t off = (size_t)v * F2 + t * 2;
    float2 h = *(const float2*)(h2 + off);
    const float w0 = dv * dv;
    float ax = h.x * w0, ay = h.y * w0;
    int cnt = deg[v]; if (cnt > CAP) cnt = CAP;
    const int* bk = bucket + (size_t)v * CAP;
    for (int j = 0; j < cnt; ++j) {
        int s = bk[j];
        float w = dinv[s] * dv;
        float2 hs = *(const float2*)(h2 + (size_t)s * F2 + t * 2);
        ax += hs.x * w; ay += hs.y * w;
    }
    float2 bb = *(const float2*)(b2 + t * 2);
    ax += bb.x; ay += bb.y;
    float m = fmaxf(ax, ay);
#pragma unroll
    for (int o = 32; o >= 1; o >>= 1) m = fmaxf(m, __shfl_xor(m, o, 64));
    float ex = expf(ax - m), ey = expf(ay - m);
    float s = ex + ey;
#pragma unroll
    for (int o = 32; o >= 1; o >>= 1) s += __shfl_xor(s, o, 64);
    float inv = 1.0f / s;
    *(float2*)(out + off) = make_float2(ex * inv, ey * inv);
}

// ======= launch =======
extern "C" void kernel_launch(void* const* d_in, const int* in_sizes, int n_in,
                              void* d_out, int out_size, void* d_ws, size_t ws_size,
                              hipStream_t stream) {
    const float* x  = (const float*)d_in[0];
    const int*   ei = (const int*)d_in[1];
    const float* W1 = (const float*)d_in[2];
    const float* b1 = (const float*)d_in[3];
    const float* W2 = (const float*)d_in[4];
    const float* b2 = (const float*)d_in[5];
    float* out = (float*)d_out;

    char* ws = (char*)d_ws;
    size_t o = 0;
    auto alloc = [&](size_t bytes) -> char* {
        char* p = ws + o;
        o += (bytes + 511) & ~(size_t)511;
        return p;
    };
    int*            flag   = (int*)           alloc(4);
    int*            cursor = (int*)           alloc((size_t)N_NODES * 4);
    float*          dinv   = (float*)         alloc((size_t)N_NODES * 4);
    int*            bucket = (int*)           alloc((size_t)N_NODES * CAP * 4);
    unsigned short* w1t    = (unsigned short*)alloc((size_t)F1 * F0 * 2);
    float*          h1     = (float*)         alloc((size_t)N_NODES * F1 * 4);
    float*          a1     = (float*)         alloc((size_t)N_NODES * F1 * 4);

    r8_zero<<<(N_NODES + 255) / 256, 256, 0, stream>>>(cursor, N_NODES);
    r8_detect<<<1, 64, 0, stream>>>((const uint32_t*)ei, flag);
    r8_fill<<<(N_EDGES + 255) / 256, 256, 0, stream>>>(ei, flag, cursor, bucket);
    r8_dinv<<<(N_NODES + 255) / 256, 256, 0, stream>>>(cursor, dinv);
    r8_w1t<<<F0, F1, 0, stream>>>(W1, w1t);

    dim3 g1((N_NODES + 127) / 128, F1 / 128);
    r8_gemm1<<<g1, 256, 0, stream>>>(x, w1t, h1, N_NODES);

    r8_prop1<<<N_NODES, 64, 0, stream>>>(h1, bucket, cursor, dinv, b1, a1);

    float* h2 = h1;  // h1 dead after prop1
    dim3 g2((N_NODES + 63) / 64, F2 / 64);
    r8_sgemm<<<g2, 256, 0, stream>>>(a1, W2, h2, N_NODES, F2, F1);

    r8_prop2<<<N_NODES, 64, 0, stream>>>(h2, bucket, cursor, dinv, b2, out);
}